// Round 1
// baseline (603.617 us; speedup 1.0000x reference)
//
#include <hip/hip_runtime.h>

// Problem constants (B groups, T timesteps, S states, M measurements)
#define NB 1024
#define NT 256
#define NS 16
#define NM 4
#define NSTEP 255            // T-1 gain/recursion steps

// Workspace layout (floats)
#define AB_STRIDE 320        // 256 (A^T) + 64 (B) per step
#define Z0_OFF (NSTEP * AB_STRIDE)   // 81600
#define OUT0_OFF (Z0_OFF + 16)       // 81616
// total ws use: 81620 floats = ~327 KB

// -----------------------------------------------------------------------------
// Kernel 1: shared Riccati recursion. Single block of 256 threads.
// Computes A_t = F(I - K_t H), B_t = F K_t for t = 0..254 and
// P_{t+1} = A_t P_t A_t^T + B_t R B_t^T + Q   (Joseph form folded with predict)
// Also z0 = F x0 and out0 = H z0.
// P is symmetric, so all 16-deep dot products are arranged row*row.
// -----------------------------------------------------------------------------
__global__ __launch_bounds__(256) void riccati_kernel(
    const float* __restrict__ Fg, const float* __restrict__ Hg,
    const float* __restrict__ Qg, const float* __restrict__ Rg,
    const float* __restrict__ x0g, const float* __restrict__ sdg,
    float* __restrict__ ws)
{
    __shared__ float sF[256], sH[64], sQ[256], sR[16];
    __shared__ float sP[16 * 17];
    __shared__ float sHP[64], sS[16], sCof[16], sSinv[16], sKT[64];
    __shared__ float sImKHT[16 * 17], sA[16 * 17], sB[64], sRBt[64], sAP[16 * 17];
    __shared__ float sz0[16];

    const int tid = threadIdx.x;
    const int i = tid >> 4;      // row 0..15
    const int j = tid & 15;      // col 0..15

    sF[tid] = Fg[tid];
    sQ[tid] = Qg[tid];
    if (tid < 64) sH[tid] = Hg[tid];
    if (tid < 16) sR[tid] = Rg[tid];
    __syncthreads();

    // P = F diag(sd^2) F^T + Q
    {
        float acc = sQ[tid];
#pragma unroll
        for (int k = 0; k < 16; ++k) {
            float sd = sdg[k];
            acc += sF[i * 16 + k] * (sd * sd) * sF[j * 16 + k];
        }
        sP[i * 17 + j] = acc;
    }
    // z0 = F x0
    if (tid < 16) {
        float acc = 0.f;
#pragma unroll
        for (int k = 0; k < 16; ++k) acc += sF[tid * 16 + k] * x0g[k];
        sz0[tid] = acc;
        ws[Z0_OFF + tid] = acc;
    }
    __syncthreads();
    // out0 = H z0
    if (tid < 4) {
        float acc = 0.f;
#pragma unroll
        for (int k = 0; k < 16; ++k) acc += sH[tid * 16 + k] * sz0[k];
        ws[OUT0_OFF + tid] = acc;
    }
    // (sP already synced above; first loop stage only reads sP/sH)

    for (int t = 0; t < NSTEP; ++t) {
        // 1. HP[m][s] = sum_k H[m][k] P[s][k]   (P symmetric)
        if (tid < 64) {
            int m = tid >> 4, s = tid & 15;
            float acc = 0.f;
#pragma unroll
            for (int k = 0; k < 16; ++k) acc += sH[m * 16 + k] * sP[s * 17 + k];
            sHP[m * 16 + s] = acc;
        }
        __syncthreads();
        // 2. S[m][n] = sum_s HP[m][s] H[n][s] + R[m][n]
        if (tid < 16) {
            int m = tid >> 2, n = tid & 3;
            float acc = sR[m * 4 + n];
#pragma unroll
            for (int s = 0; s < 16; ++s) acc += sHP[m * 16 + s] * sH[n * 16 + s];
            sS[m * 4 + n] = acc;
        }
        __syncthreads();
        // 3a. cofactors of S (4x4)
        if (tid < 16) {
            int r = tid >> 2, c = tid & 3;
            int r0 = (r == 0) ? 1 : 0, r1 = (r <= 1) ? 2 : 1, r2 = (r <= 2) ? 3 : 2;
            int c0 = (c == 0) ? 1 : 0, c1 = (c <= 1) ? 2 : 1, c2 = (c <= 2) ? 3 : 2;
            float a = sS[r0 * 4 + c0], b = sS[r0 * 4 + c1], cc = sS[r0 * 4 + c2];
            float d = sS[r1 * 4 + c0], e = sS[r1 * 4 + c1], f  = sS[r1 * 4 + c2];
            float g = sS[r2 * 4 + c0], h = sS[r2 * 4 + c1], ii = sS[r2 * 4 + c2];
            float det3 = a * (e * ii - f * h) - b * (d * ii - f * g) + cc * (d * h - e * g);
            sCof[r * 4 + c] = ((r + c) & 1) ? -det3 : det3;
        }
        __syncthreads();
        // 3b. Sinv = adj(S)/det = Cof^T / det
        if (tid < 16) {
            int r = tid >> 2, c = tid & 3;
            float det = sS[0] * sCof[0] + sS[1] * sCof[1] + sS[2] * sCof[2] + sS[3] * sCof[3];
            sSinv[c * 4 + r] = sCof[r * 4 + c] / det;
        }
        __syncthreads();
        // 4. KT[m][s] = sum_n Sinv[m][n] HP[n][s]   (K^T = S^{-1} H P)
        if (tid < 64) {
            int m = tid >> 4, s = tid & 15;
            float acc = 0.f;
#pragma unroll
            for (int n = 0; n < 4; ++n) acc += sSinv[m * 4 + n] * sHP[n * 16 + s];
            sKT[m * 16 + s] = acc;
        }
        __syncthreads();
        // 5. ImKHT[j][i] = delta_ij - sum_m KT[m][i] H[m][j]  (stored transposed)
        {
            float acc = (i == j) ? 1.f : 0.f;
#pragma unroll
            for (int m = 0; m < 4; ++m) acc -= sKT[m * 16 + i] * sH[m * 16 + j];
            sImKHT[j * 17 + i] = acc;
        }
        __syncthreads();
        // 6. A[i][j] = sum_k F[i][k] ImKHT[j][k];  B[i2][m] = sum_s F[i2][s] KT[m][s]
        {
            float acc = 0.f;
#pragma unroll
            for (int k = 0; k < 16; ++k) acc += sF[i * 16 + k] * sImKHT[j * 17 + k];
            sA[i * 17 + j] = acc;
            // store A TRANSPOSED to ws for conflict-free reads in phase 2
            ws[t * AB_STRIDE + j * 16 + i] = acc;
        }
        if (tid < 64) {
            int i2 = tid >> 2, m = tid & 3;
            float acc = 0.f;
#pragma unroll
            for (int s = 0; s < 16; ++s) acc += sF[i2 * 16 + s] * sKT[m * 16 + s];
            sB[i2 * 4 + m] = acc;
            ws[t * AB_STRIDE + 256 + i2 * 4 + m] = acc;
        }
        __syncthreads();
        // 7. AP[i][j] = sum_k A[i][k] P[j][k];  RBt[m][j2] = sum_n R[m][n] B[j2][n]
        {
            float acc = 0.f;
#pragma unroll
            for (int k = 0; k < 16; ++k) acc += sA[i * 17 + k] * sP[j * 17 + k];
            sAP[i * 17 + j] = acc;
        }
        if (tid < 64) {
            int m = tid >> 4, j2 = tid & 15;
            float acc = 0.f;
#pragma unroll
            for (int n = 0; n < 4; ++n) acc += sR[m * 4 + n] * sB[j2 * 4 + n];
            sRBt[m * 16 + j2] = acc;
        }
        __syncthreads();
        // 8. P = AP A^T + B RBt + Q
        {
            float acc = sQ[i * 16 + j];
#pragma unroll
            for (int k = 0; k < 16; ++k) acc += sAP[i * 17 + k] * sA[j * 17 + k];
#pragma unroll
            for (int m = 0; m < 4; ++m) acc += sB[i * 4 + m] * sRBt[m * 16 + j];
            sP[i * 17 + j] = acc;
        }
        __syncthreads();
    }
}

// -----------------------------------------------------------------------------
// Kernel 2: batched linear state recursion.
// 256 blocks x 64 threads; each wave handles 4 batches (16 lanes per batch).
// z_t = A_{t-1} z_{t-1} + B_{t-1} obs_{t-1};  out[b,t] = H z_t.
// A/B staged from ws in 8-step LDS chunks.
// -----------------------------------------------------------------------------
__global__ __launch_bounds__(64) void filter_kernel(
    const float* __restrict__ obs, const float* __restrict__ Hg,
    const float* __restrict__ ws, float* __restrict__ out)
{
    __shared__ float sH[64];
    __shared__ float zb[64];             // 4 groups x 16 states
    __shared__ float sAB[8 * AB_STRIDE]; // 8-step chunk of (A^T | B)

    const int tid = threadIdx.x;
    const int g = tid >> 4;    // batch group within wave (0..3)
    const int i = tid & 15;    // state index
    const int b = blockIdx.x * 4 + g;

    sH[tid] = Hg[tid];
    zb[g * 16 + i] = ws[Z0_OFF + i];
    if (i < 4) out[b * (NT * NM) + i] = ws[OUT0_OFF + i];

    const float4* obs4 = (const float4*)obs;   // [B][T] of float4 (M=4)

    for (int chunk = 0; chunk < NSTEP; chunk += 8) {
        int nsteps = NSTEP - chunk; if (nsteps > 8) nsteps = 8;
        __syncthreads();
        {   // stage nsteps*320 floats as float4s
            const float4* src = (const float4*)(ws + chunk * AB_STRIDE);
            float4* dst = (float4*)sAB;
            int n4 = nsteps * (AB_STRIDE / 4);
            for (int u = tid; u < n4; u += 64) dst[u] = src[u];
        }
        __syncthreads();
        for (int ss = 0; ss < nsteps; ++ss) {
            const int s = chunk + ss;          // step index; produces out time t=s+1
            const float* AT = sAB + ss * AB_STRIDE;        // A^T: [j][i]
            const float* Bm = AT + 256;                    // B: [i][m]
            float4 o = obs4[b * NT + s];
            float zn = 0.f;
#pragma unroll
            for (int jj = 0; jj < 16; ++jj) zn += AT[jj * 16 + i] * zb[g * 16 + jj];
            float4 bb = ((const float4*)Bm)[i];
            zn += bb.x * o.x + bb.y * o.y + bb.z * o.z + bb.w * o.w;
            __syncthreads();
            zb[g * 16 + i] = zn;
            __syncthreads();
            if (i < 4) {
                float acc = 0.f;
#pragma unroll
                for (int k = 0; k < 16; ++k) acc += sH[i * 16 + k] * zb[g * 16 + k];
                out[b * (NT * NM) + (s + 1) * NM + i] = acc;
            }
        }
    }
}

extern "C" void kernel_launch(void* const* d_in, const int* in_sizes, int n_in,
                              void* d_out, int out_size, void* d_ws, size_t ws_size,
                              hipStream_t stream) {
    const float* obs = (const float*)d_in[0];   // [B,T,M]
    const float* F   = (const float*)d_in[1];   // [S,S]
    const float* H   = (const float*)d_in[2];   // [M,S]
    const float* Q   = (const float*)d_in[3];   // [S,S]
    const float* R   = (const float*)d_in[4];   // [M,M]
    const float* x0  = (const float*)d_in[5];   // [S]
    const float* sd  = (const float*)d_in[6];   // [S]
    float* ws  = (float*)d_ws;
    float* out = (float*)d_out;

    hipLaunchKernelGGL(riccati_kernel, dim3(1), dim3(256), 0, stream,
                       F, H, Q, R, x0, sd, ws);
    hipLaunchKernelGGL(filter_kernel, dim3(256), dim3(64), 0, stream,
                       obs, H, ws, out);
}

// Round 4
// 482.139 us; speedup vs baseline: 1.2520x; 1.2520x over previous
//
#include <hip/hip_runtime.h>

// B=1024 groups, T=256 steps, S=16 states, M=4 measurements
#define NT 256
#define NSTEP 255
#define AB_STRIDE 320                 // 256 (A row-major) + 64 (B) floats per step
#define Z0_OFF (NSTEP * AB_STRIDE)    // 81600
#define OUT0_OFF (Z0_OFF + 16)        // 81616
#define CONV_EPS 3e-7f

__device__ __forceinline__ float dot4(float4 a, float4 b) {
    return a.x*b.x + a.y*b.y + a.z*b.z + a.w*b.w;
}

// -----------------------------------------------------------------------------
// Kernel 1: shared Riccati recursion, SINGLE WAVE (64 threads), JOSEPH form
// (R2's standard form lost PSD in fp32 and NaN'd — Joseph is the stable one).
// Per step, 5 LDS stages:
//   s1: TF = F*P, HP = H*P          (P symmetric -> all dots are row*row)
//   s2: V = TF*H^T, S = HP*H^T + R
//   s3: B = V*S^{-1}                (per-lane 4x4 cofactors/adjugate)
//   s4: A = F - B*H (-> ws), AP = A*P = TF - B*HP, RBt = R*B^T
//   s5: P' = AP*A^T + B*RBt + Q     (Joseph: A P A^T + B R B^T + Q), conv check
// Early-exit when max|dP| < eps; tail A/B slots filled with converged values.
// -----------------------------------------------------------------------------
__global__ __launch_bounds__(64) void riccati_kernel(
    const float* __restrict__ Fg, const float* __restrict__ Hg,
    const float* __restrict__ Qg, const float* __restrict__ Rg,
    const float* __restrict__ x0g, const float* __restrict__ sdg,
    float* __restrict__ ws)
{
    __shared__ float4 sF4[80];    // F, row stride 20 floats
    __shared__ float4 sP4[80];    // P (predicted covariance), stride 20
    __shared__ float4 sTF4[80];   // TF = F*P, stride 20 (reused by fill)
    __shared__ float4 sA4[80];    // A = F - B*H, stride 20
    __shared__ float4 sAP4[80];   // AP = A*P, stride 20
    __shared__ float4 sHP4[16];   // HP [m][s]
    __shared__ float4 sRBt4[16];  // RBt [m][s]
    __shared__ float4 sS4[4];     // S 4x4
    __shared__ float4 sV4[16];    // V [i][m]
    __shared__ float4 sB4[16];    // B [i][m]
    __shared__ float  sH[64];     // H [m][s]

    float* sF   = (float*)sF4;
    float* sP   = (float*)sP4;
    float* sTF  = (float*)sTF4;
    float* sA   = (float*)sA4;
    float* sAP  = (float*)sAP4;
    float* sV   = (float*)sV4;
    float* sS   = (float*)sS4;
    float* sHP  = (float*)sHP4;
    float* sRBt = (float*)sRBt4;
    float* sB   = (float*)sB4;

    const int tid = threadIdx.x;
    const int q  = tid >> 4;      // row quad 0..3
    const int j  = tid & 15;      // column
    const int bi = tid >> 2;      // B row 0..15
    const int bm = tid & 3;       // B col / S row 0..3

    const float4* Fg4 = (const float4*)Fg;
    const float4* Hg4 = (const float4*)Hg;
    const float4* Rg4 = (const float4*)Rg;
    float4* wsf4 = (float4*)ws;

    // stage F (stride 20) and H into LDS
    for (int u = tid; u < 256; u += 64) sF[(u >> 4) * 20 + (u & 15)] = Fg[u];
    sH[tid] = Hg[tid];

    // per-lane register preloads (grid=1: occupancy irrelevant, spend VGPRs)
    float4 zF[4][4], zFj[4], zHq[4], zHn[4];
#pragma unroll
    for (int r = 0; r < 4; ++r)
#pragma unroll
        for (int f = 0; f < 4; ++f) zF[r][f] = Fg4[(q + 4*r)*4 + f];
#pragma unroll
    for (int f = 0; f < 4; ++f) {
        zFj[f] = Fg4[j*4 + f];    // F row j   (init only)
        zHq[f] = Hg4[q*4 + f];    // H row q   (HP)
        zHn[f] = Hg4[bm*4 + f];   // H row bm  (V, S)
    }
    float zQ[4];
#pragma unroll
    for (int r = 0; r < 4; ++r) zQ[r] = Qg[(q + 4*r)*16 + j];
    float  zR  = Rg[tid & 15];    // R[tid] for tid<16 (S stage)
    float4 zRq = Rg4[q];          // R row q (RBt stage)
    float4 zSd2[4];
#pragma unroll
    for (int f = 0; f < 4; ++f) {
        float4 s = ((const float4*)sdg)[f];
        zSd2[f] = make_float4(s.x*s.x, s.y*s.y, s.z*s.z, s.w*s.w);
    }
    __syncthreads();

    // P = F diag(sd^2) F^T + Q   (predicted covariance at t=0)
#pragma unroll
    for (int r = 0; r < 4; ++r) {
        float acc = zQ[r];
#pragma unroll
        for (int f = 0; f < 4; ++f) {
            float4 a = zF[r][f], b = zFj[f], s = zSd2[f];
            acc += a.x*s.x*b.x + a.y*s.y*b.y + a.z*s.z*b.z + a.w*s.w*b.w;
        }
        sP[(q + 4*r)*20 + j] = acc;
    }
    // z0 = F x0 (stash in sV temporarily), out0 = H z0
    if (tid < 16) {
        float acc = 0.f;
#pragma unroll
        for (int f = 0; f < 4; ++f) {
            float4 fr = ((float4*)(sF + tid*20))[f];
            float4 xv = ((const float4*)x0g)[f];
            acc += dot4(fr, xv);
        }
        sV[tid] = acc;
        ws[Z0_OFF + tid] = acc;
    }
    __syncthreads();
    if (tid < 4) {
        float acc = 0.f;
#pragma unroll
        for (int k = 0; k < 16; ++k) acc += sH[tid*16 + k] * sV[k];
        ws[OUT0_OFF + tid] = acc;
    }
    __syncthreads();

    float aval[4] = {0.f, 0.f, 0.f, 0.f};
    int t;
    for (t = 0; t < NSTEP; ++t) {
        // ---- s1: TF rows q+4r, HP row q (each lane reads P row j once) ----
        float4 zP[4];
#pragma unroll
        for (int f = 0; f < 4; ++f) zP[f] = sP4[j*5 + f];
        float tf[4], hp = 0.f;
#pragma unroll
        for (int r = 0; r < 4; ++r) {
            float acc = 0.f;
#pragma unroll
            for (int f = 0; f < 4; ++f) acc += dot4(zF[r][f], zP[f]);
            tf[r] = acc;
        }
#pragma unroll
        for (int f = 0; f < 4; ++f) hp += dot4(zHq[f], zP[f]);
#pragma unroll
        for (int r = 0; r < 4; ++r) sTF[(q + 4*r)*20 + j] = tf[r];
        sHP[q*16 + j] = hp;
        __syncthreads();

        // ---- s2: V = TF*H^T, S = HP*H^T + R ----
        {
            float acc = 0.f;
#pragma unroll
            for (int f = 0; f < 4; ++f) acc += dot4(sTF4[bi*5 + f], zHn[f]);
            sV[bi*4 + bm] = acc;
        }
        if (tid < 16) {
            float acc = zR;
#pragma unroll
            for (int f = 0; f < 4; ++f) acc += dot4(sHP4[(tid >> 2)*4 + f], zHn[f]);
            sS[tid] = acc;
        }
        __syncthreads();

        // ---- s3: B[bi][bm] via cofactors of S row bm ----
        {
            int ra = (bm == 0) ? 1 : 0;
            int rb = (bm <= 1) ? 2 : 1;
            int rc = (bm <= 2) ? 3 : 2;
            float4 a = sS4[ra], b = sS4[rb], c = sS4[rc], sm = sS4[bm];
            float M0 = a.y*(b.z*c.w - b.w*c.z) - a.z*(b.y*c.w - b.w*c.y) + a.w*(b.y*c.z - b.z*c.y);
            float M1 = a.x*(b.z*c.w - b.w*c.z) - a.z*(b.x*c.w - b.w*c.x) + a.w*(b.x*c.z - b.z*c.x);
            float M2 = a.x*(b.y*c.w - b.w*c.y) - a.y*(b.x*c.w - b.w*c.x) + a.w*(b.x*c.y - b.y*c.x);
            float M3 = a.x*(b.y*c.z - b.z*c.y) - a.y*(b.x*c.z - b.z*c.x) + a.z*(b.x*c.y - b.y*c.x);
            float sg = (bm & 1) ? -1.f : 1.f;
            float c0 = sg*M0, c1 = -sg*M1, c2 = sg*M2, c3 = -sg*M3;
            float det = sm.x*c0 + sm.y*c1 + sm.z*c2 + sm.w*c3;
            float4 vv = sV4[bi];
            float bval = (vv.x*c0 + vv.y*c1 + vv.z*c2 + vv.w*c3) / det;
            sB[tid] = bval;
            ws[t*AB_STRIDE + 256 + tid] = bval;
        }
        __syncthreads();

        // ---- s4: A = F - B*H (-> ws), AP = TF - B*HP, RBt = R*B^T ----
        {
            float h0 = sH[j],  h1 = sH[16 + j],  h2 = sH[32 + j],  h3 = sH[48 + j];
            float p0 = sHP[j], p1 = sHP[16 + j], p2 = sHP[32 + j], p3 = sHP[48 + j];
#pragma unroll
            for (int r = 0; r < 4; ++r) {
                int i = q + 4*r;
                float4 bb = sB4[i];
                float av = sF[i*20 + j] - (bb.x*h0 + bb.y*h1 + bb.z*h2 + bb.w*h3);
                aval[r] = av;
                sA[i*20 + j] = av;
                ws[t*AB_STRIDE + i*16 + j] = av;
                sAP[i*20 + j] = tf[r] - (bb.x*p0 + bb.y*p1 + bb.z*p2 + bb.w*p3);
            }
            sRBt[q*16 + j] = dot4(zRq, sB4[j]);
        }
        __syncthreads();

        // ---- s5: P' = AP*A^T + B*RBt + Q (Joseph), convergence check ----
        float4 zA[4];
#pragma unroll
        for (int f = 0; f < 4; ++f) zA[f] = sA4[j*5 + f];
        float rb0 = sRBt[j], rb1 = sRBt[16 + j], rb2 = sRBt[32 + j], rb3 = sRBt[48 + j];
        float dmax = 0.f;
#pragma unroll
        for (int r = 0; r < 4; ++r) {
            int i = q + 4*r;
            float4 bb = sB4[i];
            float acc = zQ[r] + bb.x*rb0 + bb.y*rb1 + bb.z*rb2 + bb.w*rb3;
#pragma unroll
            for (int f = 0; f < 4; ++f) acc += dot4(sAP4[i*5 + f], zA[f]);
            float po = sP[i*20 + j];
            sP[i*20 + j] = acc;
            dmax = fmaxf(dmax, fabsf(acc - po));
        }
        __syncthreads();
        if (t >= 24 && __all(dmax < CONV_EPS)) { ++t; break; }
    }

    // fill remaining steps with the converged A/B (coalesced float4 stores)
    if (t < NSTEP) {
#pragma unroll
        for (int r = 0; r < 4; ++r) sTF[(q + 4*r)*16 + j] = aval[r];
        __syncthreads();
        float4 fa = ((float4*)sTF)[tid];
        float4 fb = sB4[tid & 15];
        for (int tt = t; tt < NSTEP; ++tt) {
            wsf4[tt*80 + tid] = fa;
            if (tid < 16) wsf4[tt*80 + 64 + tid] = fb;
        }
    }
}

// -----------------------------------------------------------------------------
// Kernel 2: batched linear recursion z' = A z + B obs, out = H z.
// 256 blocks x 64 threads (1 wave), 4 batches/block, 16 lanes/batch.
// A (stride-20 rows), B, and OBS staged per 16-step chunk -> no cold global
// loads on the critical path. H rows in registers.
// -----------------------------------------------------------------------------
__global__ __launch_bounds__(64) void filter_kernel(
    const float* __restrict__ obs, const float* __restrict__ Hg,
    const float* __restrict__ ws, float* __restrict__ out)
{
    __shared__ float4 sA4[16 * 80];   // [ss][row][20 floats] = 20 KB
    __shared__ float4 sB4[16 * 16];   // [ss][i] float4
    __shared__ float4 sObs4[16 * 4];  // [ss][g] float4
    __shared__ float4 zb4[16];        // 4 groups x 16 states

    float* sA = (float*)sA4;
    float* zb = (float*)zb4;

    const int tid = threadIdx.x;
    const int g = tid >> 4;           // batch group 0..3
    const int i = tid & 15;           // state index
    const int b = blockIdx.x * 4 + g;

    // H row (i&3) in registers (only lanes i<4 use it for output)
    const float4* Hg4 = (const float4*)Hg;
    float4 zH[4];
#pragma unroll
    for (int f = 0; f < 4; ++f) zH[f] = Hg4[(i & 3)*4 + f];

    zb[g*16 + i] = ws[Z0_OFF + i];
    if (i < 4) out[b * (NT * 4) + i] = ws[OUT0_OFF + i];

    const float4* wsf4 = (const float4*)ws;
    const float4* obs4 = (const float4*)obs;

    for (int chunk = 0; chunk < NSTEP; chunk += 16) {
        int nsteps = NSTEP - chunk; if (nsteps > 16) nsteps = 16;
        __syncthreads();
        // stage A rows (restride 16 -> 20 for bank-conflict-free b128 reads)
        for (int u = tid; u < nsteps * 64; u += 64) {
            int ss = u >> 6, rem = u & 63, row = rem >> 2, f = rem & 3;
            sA4[ss*80 + row*5 + f] = wsf4[(chunk + ss)*80 + rem];
        }
        for (int u = tid; u < nsteps * 16; u += 64) {
            int ss = u >> 4, r2 = u & 15;
            sB4[ss*16 + r2] = wsf4[(chunk + ss)*80 + 64 + r2];
        }
        if (tid < nsteps * 4) {
            int ss = tid >> 2, gg = tid & 3;
            sObs4[ss*4 + gg] = obs4[(blockIdx.x*4 + gg) * NT + chunk + ss];
        }
        __syncthreads();
        for (int ss = 0; ss < nsteps; ++ss) {
            const float4* Ar = (const float4*)(sA + ss*320 + i*20);
            float4 a0 = Ar[0], a1 = Ar[1], a2 = Ar[2], a3 = Ar[3];
            float4 z0 = zb4[g*4 + 0], z1 = zb4[g*4 + 1],
                   z2 = zb4[g*4 + 2], z3 = zb4[g*4 + 3];
            float4 bb = sB4[ss*16 + i];
            float4 oo = sObs4[ss*4 + g];
            float zn = dot4(a0, z0) + dot4(a1, z1) + dot4(a2, z2) + dot4(a3, z3)
                     + dot4(bb, oo);
            __syncthreads();
            zb[g*16 + i] = zn;
            __syncthreads();
            if (i < 4) {
                float4 w0 = zb4[g*4 + 0], w1 = zb4[g*4 + 1],
                       w2 = zb4[g*4 + 2], w3 = zb4[g*4 + 3];
                float o = dot4(zH[0], w0) + dot4(zH[1], w1)
                        + dot4(zH[2], w2) + dot4(zH[3], w3);
                out[b * (NT * 4) + (chunk + ss + 1)*4 + i] = o;
            }
        }
    }
}

extern "C" void kernel_launch(void* const* d_in, const int* in_sizes, int n_in,
                              void* d_out, int out_size, void* d_ws, size_t ws_size,
                              hipStream_t stream) {
    const float* obs = (const float*)d_in[0];   // [B,T,M]
    const float* F   = (const float*)d_in[1];   // [S,S]
    const float* H   = (const float*)d_in[2];   // [M,S]
    const float* Q   = (const float*)d_in[3];   // [S,S]
    const float* R   = (const float*)d_in[4];   // [M,M]
    const float* x0  = (const float*)d_in[5];   // [S]
    const float* sd  = (const float*)d_in[6];   // [S]
    float* ws  = (float*)d_ws;
    float* out = (float*)d_out;

    hipLaunchKernelGGL(riccati_kernel, dim3(1), dim3(64), 0, stream,
                       F, H, Q, R, x0, sd, ws);
    hipLaunchKernelGGL(filter_kernel, dim3(256), dim3(64), 0, stream,
                       obs, H, ws, out);
}

// Round 5
// 418.794 us; speedup vs baseline: 1.4413x; 1.1513x over previous
//
#include <hip/hip_runtime.h>

// B=1024 groups, T=256 steps, S=16 states, M=4 measurements
#define NT 256
#define NSTEP 255
#define AB_STRIDE 320                 // 256 (A row-major) + 64 (B) floats per step
#define Z0_OFF (NSTEP * AB_STRIDE)    // 81600
#define OUT0_OFF (Z0_OFF + 16)        // 81616
#define CONV_EPS 2e-5f                // R4's 3e-7 was below fp32 jitter -> never fired

__device__ __forceinline__ float dot4(float4 a, float4 b) {
    return a.x*b.x + a.y*b.y + a.z*b.z + a.w*b.w;
}

// -----------------------------------------------------------------------------
// Kernel 1: shared Riccati recursion, SINGLE WAVE (64 threads), Joseph form.
// R5: NO global stores inside the barriered step loop — A/B go to a 16-step
// LDS chunk buffer, flushed with coalesced float4 stores once per chunk
// (one vmcnt-drain per 16 steps instead of 5 per step).
// Stages: s1 TF=F*P, HP=H*P | s2 V=TF*H^T, S=HP*H^T+R | s3 B=V*S^{-1}
//         s4 A=F-B*H, AP=TF-B*HP, RBt=R*B^T | s5 P'=AP*A^T+B*RBt+Q + conv.
// Early-exit when max|dP| < 2e-5; tail A/B filled with converged values.
// -----------------------------------------------------------------------------
__global__ __launch_bounds__(64) void riccati_kernel(
    const float* __restrict__ Fg, const float* __restrict__ Hg,
    const float* __restrict__ Qg, const float* __restrict__ Rg,
    const float* __restrict__ x0g, const float* __restrict__ sdg,
    float* __restrict__ ws)
{
    __shared__ float4 sF4[80];    // F, row stride 20 floats
    __shared__ float4 sP4[80];    // P, stride 20
    __shared__ float4 sTF4[80];   // TF = F*P, stride 20 (reused by fill)
    __shared__ float4 sA4[80];    // A, stride 20
    __shared__ float4 sAP4[80];   // AP = A*P, stride 20
    __shared__ float4 sHP4[16];   // HP [m][s]
    __shared__ float4 sRBt4[16];  // RBt [m][s]
    __shared__ float4 sS4[4];     // S 4x4
    __shared__ float4 sV4[16];    // V [i][m]
    __shared__ float4 sB4[16];    // B [i][m]
    __shared__ float  sH[64];     // H [m][s]
    __shared__ float4 sABbuf4[16 * 80];  // 16-step chunk of (A dense | B) = 20 KB

    float* sF   = (float*)sF4;
    float* sP   = (float*)sP4;
    float* sTF  = (float*)sTF4;
    float* sA   = (float*)sA4;
    float* sAP  = (float*)sAP4;
    float* sV   = (float*)sV4;
    float* sS   = (float*)sS4;
    float* sHP  = (float*)sHP4;
    float* sRBt = (float*)sRBt4;
    float* sB   = (float*)sB4;
    float* sABf = (float*)sABbuf4;

    const int tid = threadIdx.x;
    const int q  = tid >> 4;      // row quad 0..3
    const int j  = tid & 15;      // column
    const int bi = tid >> 2;      // B row 0..15
    const int bm = tid & 3;       // B col / S row 0..3

    const float4* Fg4 = (const float4*)Fg;
    const float4* Hg4 = (const float4*)Hg;
    const float4* Rg4 = (const float4*)Rg;
    float4* wsf4 = (float4*)ws;

    // stage F (stride 20) and H into LDS
    for (int u = tid; u < 256; u += 64) sF[(u >> 4) * 20 + (u & 15)] = Fg[u];
    sH[tid] = Hg[tid];

    // per-lane register preloads (grid=1: occupancy irrelevant, spend VGPRs)
    float4 zF[4][4], zFj[4], zHq[4], zHn[4];
#pragma unroll
    for (int r = 0; r < 4; ++r)
#pragma unroll
        for (int f = 0; f < 4; ++f) zF[r][f] = Fg4[(q + 4*r)*4 + f];
#pragma unroll
    for (int f = 0; f < 4; ++f) {
        zFj[f] = Fg4[j*4 + f];    // F row j   (init only)
        zHq[f] = Hg4[q*4 + f];    // H row q   (HP)
        zHn[f] = Hg4[bm*4 + f];   // H row bm  (V, S)
    }
    float zQ[4];
#pragma unroll
    for (int r = 0; r < 4; ++r) zQ[r] = Qg[(q + 4*r)*16 + j];
    float  zR  = Rg[tid & 15];    // R[tid] for tid<16 (S stage)
    float4 zRq = Rg4[q];          // R row q (RBt stage)
    float4 zSd2[4];
#pragma unroll
    for (int f = 0; f < 4; ++f) {
        float4 s = ((const float4*)sdg)[f];
        zSd2[f] = make_float4(s.x*s.x, s.y*s.y, s.z*s.z, s.w*s.w);
    }
    __syncthreads();

    // P = F diag(sd^2) F^T + Q   (predicted covariance at t=0)
#pragma unroll
    for (int r = 0; r < 4; ++r) {
        float acc = zQ[r];
#pragma unroll
        for (int f = 0; f < 4; ++f) {
            float4 a = zF[r][f], b = zFj[f], s = zSd2[f];
            acc += a.x*s.x*b.x + a.y*s.y*b.y + a.z*s.z*b.z + a.w*s.w*b.w;
        }
        sP[(q + 4*r)*20 + j] = acc;
    }
    // z0 = F x0 (stash in sV temporarily), out0 = H z0
    if (tid < 16) {
        float acc = 0.f;
#pragma unroll
        for (int f = 0; f < 4; ++f) {
            float4 fr = ((float4*)(sF + tid*20))[f];
            float4 xv = ((const float4*)x0g)[f];
            acc += dot4(fr, xv);
        }
        sV[tid] = acc;
        ws[Z0_OFF + tid] = acc;
    }
    __syncthreads();
    if (tid < 4) {
        float acc = 0.f;
#pragma unroll
        for (int k = 0; k < 16; ++k) acc += sH[tid*16 + k] * sV[k];
        ws[OUT0_OFF + tid] = acc;
    }
    __syncthreads();

    float aval[4] = {0.f, 0.f, 0.f, 0.f};
    int t;
    for (t = 0; t < NSTEP; ++t) {
        const int ssb = t & 15;          // slot in LDS chunk buffer
        // ---- s1: TF rows q+4r, HP row q (each lane reads P row j once) ----
        float4 zP[4];
#pragma unroll
        for (int f = 0; f < 4; ++f) zP[f] = sP4[j*5 + f];
        float tf[4], hp = 0.f;
#pragma unroll
        for (int r = 0; r < 4; ++r) {
            float acc = 0.f;
#pragma unroll
            for (int f = 0; f < 4; ++f) acc += dot4(zF[r][f], zP[f]);
            tf[r] = acc;
        }
#pragma unroll
        for (int f = 0; f < 4; ++f) hp += dot4(zHq[f], zP[f]);
#pragma unroll
        for (int r = 0; r < 4; ++r) sTF[(q + 4*r)*20 + j] = tf[r];
        sHP[q*16 + j] = hp;
        __syncthreads();

        // ---- s2: V = TF*H^T, S = HP*H^T + R ----
        {
            float acc = 0.f;
#pragma unroll
            for (int f = 0; f < 4; ++f) acc += dot4(sTF4[bi*5 + f], zHn[f]);
            sV[bi*4 + bm] = acc;
        }
        if (tid < 16) {
            float acc = zR;
#pragma unroll
            for (int f = 0; f < 4; ++f) acc += dot4(sHP4[(tid >> 2)*4 + f], zHn[f]);
            sS[tid] = acc;
        }
        __syncthreads();

        // ---- s3: B[bi][bm] via cofactors of S row bm (to LDS chunk buf) ----
        {
            int ra = (bm == 0) ? 1 : 0;
            int rb = (bm <= 1) ? 2 : 1;
            int rc = (bm <= 2) ? 3 : 2;
            float4 a = sS4[ra], b = sS4[rb], c = sS4[rc], sm = sS4[bm];
            float M0 = a.y*(b.z*c.w - b.w*c.z) - a.z*(b.y*c.w - b.w*c.y) + a.w*(b.y*c.z - b.z*c.y);
            float M1 = a.x*(b.z*c.w - b.w*c.z) - a.z*(b.x*c.w - b.w*c.x) + a.w*(b.x*c.z - b.z*c.x);
            float M2 = a.x*(b.y*c.w - b.w*c.y) - a.y*(b.x*c.w - b.w*c.x) + a.w*(b.x*c.y - b.y*c.x);
            float M3 = a.x*(b.y*c.z - b.z*c.y) - a.y*(b.x*c.z - b.z*c.x) + a.z*(b.x*c.y - b.y*c.x);
            float sg = (bm & 1) ? -1.f : 1.f;
            float c0 = sg*M0, c1 = -sg*M1, c2 = sg*M2, c3 = -sg*M3;
            float det = sm.x*c0 + sm.y*c1 + sm.z*c2 + sm.w*c3;
            float4 vv = sV4[bi];
            float bval = (vv.x*c0 + vv.y*c1 + vv.z*c2 + vv.w*c3) / det;
            sB[tid] = bval;
            sABf[ssb*320 + 256 + tid] = bval;
        }
        __syncthreads();

        // ---- s4: A = F - B*H (-> chunk buf), AP = TF - B*HP, RBt = R*B^T ----
        {
            float h0 = sH[j],  h1 = sH[16 + j],  h2 = sH[32 + j],  h3 = sH[48 + j];
            float p0 = sHP[j], p1 = sHP[16 + j], p2 = sHP[32 + j], p3 = sHP[48 + j];
#pragma unroll
            for (int r = 0; r < 4; ++r) {
                int i = q + 4*r;
                float4 bb = sB4[i];
                float av = sF[i*20 + j] - (bb.x*h0 + bb.y*h1 + bb.z*h2 + bb.w*h3);
                aval[r] = av;
                sA[i*20 + j] = av;
                sABf[ssb*320 + i*16 + j] = av;
                sAP[i*20 + j] = tf[r] - (bb.x*p0 + bb.y*p1 + bb.z*p2 + bb.w*p3);
            }
            sRBt[q*16 + j] = dot4(zRq, sB4[j]);
        }
        __syncthreads();

        // ---- s5: P' = AP*A^T + B*RBt + Q (Joseph), convergence check ----
        float4 zA[4];
#pragma unroll
        for (int f = 0; f < 4; ++f) zA[f] = sA4[j*5 + f];
        float rb0 = sRBt[j], rb1 = sRBt[16 + j], rb2 = sRBt[32 + j], rb3 = sRBt[48 + j];
        float dmax = 0.f;
#pragma unroll
        for (int r = 0; r < 4; ++r) {
            int i = q + 4*r;
            float4 bb = sB4[i];
            float acc = zQ[r] + bb.x*rb0 + bb.y*rb1 + bb.z*rb2 + bb.w*rb3;
#pragma unroll
            for (int f = 0; f < 4; ++f) acc += dot4(sAP4[i*5 + f], zA[f]);
            float po = sP[i*20 + j];
            sP[i*20 + j] = acc;
            dmax = fmaxf(dmax, fabsf(acc - po));
        }
        __syncthreads();

        // ---- chunk flush (coalesced; one vmcnt drain per 16 steps) ----
        bool conv = (t >= 32) && __all(dmax < CONV_EPS);
        if (ssb == 15 || conv || t == NSTEP - 1) {
            int cb = t & ~15, nf = ssb + 1;
            for (int ss = 0; ss < nf; ++ss) {
                float4* dst = wsf4 + (cb + ss)*80;
                const float4* src = sABbuf4 + ss*80;
                dst[tid] = src[tid];
                if (tid < 16) dst[64 + tid] = src[64 + tid];
            }
        }
        if (conv) { ++t; break; }
    }

    // fill remaining steps with the converged A/B (coalesced float4 stores)
    if (t < NSTEP) {
#pragma unroll
        for (int r = 0; r < 4; ++r) sTF[(q + 4*r)*16 + j] = aval[r];
        __syncthreads();
        float4 fa = ((float4*)sTF)[tid];
        float4 fb = sB4[tid & 15];
        for (int tt = t; tt < NSTEP; ++tt) {
            wsf4[tt*80 + tid] = fa;
            if (tid < 16) wsf4[tt*80 + 64 + tid] = fb;
        }
    }
}

// -----------------------------------------------------------------------------
// Kernel 2: batched linear recursion z' = A z + B obs, out = H z.
// 256 blocks x 64 threads (1 wave), 4 batches/block, 16 lanes/batch.
// R5: double-buffered z (1 barrier/step), outputs accumulated in LDS and
// flushed per chunk -> no global stores inside the step loop, so the
// per-step barrier drains lgkm only (no vmcnt(0) HBM-store stall).
// -----------------------------------------------------------------------------
__global__ __launch_bounds__(64) void filter_kernel(
    const float* __restrict__ obs, const float* __restrict__ Hg,
    const float* __restrict__ ws, float* __restrict__ out)
{
    __shared__ float4 sA4[16 * 80];   // [ss][row][20 floats] = 20 KB
    __shared__ float4 sB4v[16 * 16];  // [ss][i] float4
    __shared__ float4 sObs4[4 * 16];  // [g][ss] float4
    __shared__ float4 zb4[2 * 16];    // double-buffered: [buf][g][4]
    __shared__ float4 sOut4[16 * 4];  // [ss][g] float4

    float* sA   = (float*)sA4;
    float* zb   = (float*)zb4;
    float* sOut = (float*)sOut4;

    const int tid = threadIdx.x;
    const int g = tid >> 4;           // batch group 0..3
    const int i = tid & 15;           // state index
    const int b = blockIdx.x * 4 + g;

    // H row (i&3) in registers (only lanes i<4 use it for output)
    const float4* Hg4 = (const float4*)Hg;
    float4 zH[4];
#pragma unroll
    for (int f = 0; f < 4; ++f) zH[f] = Hg4[(i & 3)*4 + f];

    zb[0*64 + g*16 + i] = ws[Z0_OFF + i];
    if (i < 4) out[b * (NT * 4) + i] = ws[OUT0_OFF + i];

    const float4* wsf4 = (const float4*)ws;
    const float4* obs4 = (const float4*)obs;
    float4* out4 = (float4*)out;

    int cur = 0;
    for (int chunk = 0; chunk < NSTEP; chunk += 16) {
        int nsteps = NSTEP - chunk; if (nsteps > 16) nsteps = 16;
        __syncthreads();   // guards prev chunk's sOut flush + zb reuse
        // stage A rows (restride 16 -> 20 for conflict-free b128 reads)
        for (int u = tid; u < nsteps * 64; u += 64) {
            int ss = u >> 6, rem = u & 63, row = rem >> 2, f = rem & 3;
            sA4[ss*80 + row*5 + f] = wsf4[(chunk + ss)*80 + rem];
        }
        for (int u = tid; u < nsteps * 16; u += 64) {
            int ss = u >> 4, r2 = u & 15;
            sB4v[ss*16 + r2] = wsf4[(chunk + ss)*80 + 64 + r2];
        }
        {   // obs: ss in low lane bits -> 256B contiguous per 16-lane group
            int ss = tid & 15, gg = tid >> 4;
            if (ss < nsteps)
                sObs4[gg*16 + ss] = obs4[(blockIdx.x*4 + gg) * NT + chunk + ss];
        }
        __syncthreads();   // drains staging loads + prev flush stores (1/chunk)
        for (int ss = 0; ss < nsteps; ++ss) {
            const float4* Ar = (const float4*)(sA + ss*320 + i*20);
            float4 a0 = Ar[0], a1 = Ar[1], a2 = Ar[2], a3 = Ar[3];
            float4 z0 = zb4[cur*16 + g*4 + 0], z1 = zb4[cur*16 + g*4 + 1],
                   z2 = zb4[cur*16 + g*4 + 2], z3 = zb4[cur*16 + g*4 + 3];
            float4 bb = sB4v[ss*16 + i];
            float4 oo = sObs4[g*16 + ss];
            float zn = dot4(a0, z0) + dot4(a1, z1) + dot4(a2, z2) + dot4(a3, z3)
                     + dot4(bb, oo);
            int nxt = cur ^ 1;
            zb[nxt*64 + g*16 + i] = zn;
            __syncthreads();          // lgkm-only drain (no vmem in flight)
            if (i < 4) {
                float4 w0 = zb4[nxt*16 + g*4 + 0], w1 = zb4[nxt*16 + g*4 + 1],
                       w2 = zb4[nxt*16 + g*4 + 2], w3 = zb4[nxt*16 + g*4 + 3];
                float o = dot4(zH[0], w0) + dot4(zH[1], w1)
                        + dot4(zH[2], w2) + dot4(zH[3], w3);
                sOut[ss*16 + g*4 + i] = o;
            }
            cur = nxt;
        }
        __syncthreads();
        // flush outputs: per g, 16 consecutive float4 (256B) -> coalesced
        if (i < nsteps) out4[b * NT + chunk + 1 + i] = sOut4[i*4 + g];
    }
}

extern "C" void kernel_launch(void* const* d_in, const int* in_sizes, int n_in,
                              void* d_out, int out_size, void* d_ws, size_t ws_size,
                              hipStream_t stream) {
    const float* obs = (const float*)d_in[0];   // [B,T,M]
    const float* F   = (const float*)d_in[1];   // [S,S]
    const float* H   = (const float*)d_in[2];   // [M,S]
    const float* Q   = (const float*)d_in[3];   // [S,S]
    const float* R   = (const float*)d_in[4];   // [M,M]
    const float* x0  = (const float*)d_in[5];   // [S]
    const float* sd  = (const float*)d_in[6];   // [S]
    float* ws  = (float*)d_ws;
    float* out = (float*)d_out;

    hipLaunchKernelGGL(riccati_kernel, dim3(1), dim3(64), 0, stream,
                       F, H, Q, R, x0, sd, ws);
    hipLaunchKernelGGL(filter_kernel, dim3(256), dim3(64), 0, stream,
                       obs, H, ws, out);
}

// Round 6
// 363.692 us; speedup vs baseline: 1.6597x; 1.1515x over previous
//
#include <hip/hip_runtime.h>

// B=1024 groups, T=256 steps, S=16 states, M=4 measurements
#define NT 256
#define NSTEP 255
#define AB_STRIDE 320                 // 256 (A row-major) + 64 (B) floats per step
#define Z0_OFF (NSTEP * AB_STRIDE)    // 81600
#define OUT0_OFF (Z0_OFF + 16)        // 81616
#define FLAG_OFF 81632                // int flag (ws poison 0xAA -> negative)
#define CONV_EPS 1e-4f
#define NCHUNK 16

__device__ __forceinline__ float dot4(float4 a, float4 b) {
    return a.x*b.x + a.y*b.y + a.z*b.z + a.w*b.w;
}

// -----------------------------------------------------------------------------
// Fused kernel. Block 0: shared Riccati (Joseph form, single wave, 5 LDS
// stages/step), publishes each 16-step (A|B) chunk to ws then releases a
// monotonic flag (agent scope). Blocks 1..256: per-batch linear filter;
// spin (acquire) for chunk k, stage to LDS, then run 16 steps with z held in
// REGISTERS — A·z and H·z via 16 unrolled __shfl broadcasts (no LDS
// round-trip, no barrier on the z chain). Producer never waits on consumers;
// 257 single-wave blocks are far under residency capacity -> no deadlock.
// -----------------------------------------------------------------------------
__global__ __launch_bounds__(64) void kf_fused_kernel(
    const float* __restrict__ obs, const float* __restrict__ Fg,
    const float* __restrict__ Hg,  const float* __restrict__ Qg,
    const float* __restrict__ Rg,  const float* __restrict__ x0g,
    const float* __restrict__ sdg, float* __restrict__ ws,
    float* __restrict__ out)
{
    // ---- producer LDS ----
    __shared__ float4 sF4[80], sP4[80], sTF4[80], sA4p[80], sAP4[80];
    __shared__ float4 sHP4[16], sRBt4[16], sS4[4], sV4[16], sB4[16];
    __shared__ float  sH[64];
    __shared__ float4 sABbuf4[16 * 80];   // 16-step chunk of (A|B) = 20 KB
    // ---- consumer LDS ----
    __shared__ float4 sA4[16 * 80];       // staged A rows, stride 20 = 20 KB
    __shared__ float4 sB4v[16 * 16];
    __shared__ float4 sObs4[4 * 16];

    const int tid = threadIdx.x;
    int* flagp = (int*)ws + FLAG_OFF;

    if (blockIdx.x == 0) {
        // =================== PRODUCER: Riccati ===================
        float* sF   = (float*)sF4;   float* sP   = (float*)sP4;
        float* sTF  = (float*)sTF4;  float* sA   = (float*)sA4p;
        float* sAP  = (float*)sAP4;  float* sV   = (float*)sV4;
        float* sS   = (float*)sS4;   float* sHP  = (float*)sHP4;
        float* sRBt = (float*)sRBt4; float* sB   = (float*)sB4;
        float* sABf = (float*)sABbuf4;

        const int q  = tid >> 4;     // row quad
        const int j  = tid & 15;     // column
        const int bi = tid >> 2;     // B row
        const int bm = tid & 3;      // B col / S row

        const float4* Fg4 = (const float4*)Fg;
        const float4* Hg4 = (const float4*)Hg;
        const float4* Rg4 = (const float4*)Rg;
        float4* wsf4 = (float4*)ws;

        for (int u = tid; u < 256; u += 64) sF[(u >> 4) * 20 + (u & 15)] = Fg[u];
        sH[tid] = Hg[tid];

        float4 zF[4][4], zFj[4], zHq[4], zHn[4];
#pragma unroll
        for (int r = 0; r < 4; ++r)
#pragma unroll
            for (int f = 0; f < 4; ++f) zF[r][f] = Fg4[(q + 4*r)*4 + f];
#pragma unroll
        for (int f = 0; f < 4; ++f) {
            zFj[f] = Fg4[j*4 + f];
            zHq[f] = Hg4[q*4 + f];
            zHn[f] = Hg4[bm*4 + f];
        }
        float zQ[4];
#pragma unroll
        for (int r = 0; r < 4; ++r) zQ[r] = Qg[(q + 4*r)*16 + j];
        float  zR  = Rg[tid & 15];
        float4 zRq = Rg4[q];
        float4 zSd2[4];
#pragma unroll
        for (int f = 0; f < 4; ++f) {
            float4 s = ((const float4*)sdg)[f];
            zSd2[f] = make_float4(s.x*s.x, s.y*s.y, s.z*s.z, s.w*s.w);
        }
        __syncthreads();

        // P = F diag(sd^2) F^T + Q
#pragma unroll
        for (int r = 0; r < 4; ++r) {
            float acc = zQ[r];
#pragma unroll
            for (int f = 0; f < 4; ++f) {
                float4 a = zF[r][f], b = zFj[f], s = zSd2[f];
                acc += a.x*s.x*b.x + a.y*s.y*b.y + a.z*s.z*b.z + a.w*s.w*b.w;
            }
            sP[(q + 4*r)*20 + j] = acc;
        }
        // z0 = F x0, out0 = H z0
        if (tid < 16) {
            float acc = 0.f;
#pragma unroll
            for (int f = 0; f < 4; ++f) {
                float4 fr = ((float4*)(sF + tid*20))[f];
                float4 xv = ((const float4*)x0g)[f];
                acc += dot4(fr, xv);
            }
            sV[tid] = acc;
            ws[Z0_OFF + tid] = acc;
        }
        __syncthreads();
        if (tid < 4) {
            float acc = 0.f;
#pragma unroll
            for (int k = 0; k < 16; ++k) acc += sH[tid*16 + k] * sV[k];
            ws[OUT0_OFF + tid] = acc;
        }
        __syncthreads();

        float aval[4] = {0.f, 0.f, 0.f, 0.f};
        int t;
        for (t = 0; t < NSTEP; ++t) {
            const int ssb = t & 15;
            // s1: TF = F*P, HP = H*P
            float4 zP[4];
#pragma unroll
            for (int f = 0; f < 4; ++f) zP[f] = sP4[j*5 + f];
            float tf[4], hp = 0.f;
#pragma unroll
            for (int r = 0; r < 4; ++r) {
                float acc = 0.f;
#pragma unroll
                for (int f = 0; f < 4; ++f) acc += dot4(zF[r][f], zP[f]);
                tf[r] = acc;
            }
#pragma unroll
            for (int f = 0; f < 4; ++f) hp += dot4(zHq[f], zP[f]);
#pragma unroll
            for (int r = 0; r < 4; ++r) sTF[(q + 4*r)*20 + j] = tf[r];
            sHP[q*16 + j] = hp;
            __syncthreads();

            // s2: V = TF*H^T, S = HP*H^T + R
            {
                float acc = 0.f;
#pragma unroll
                for (int f = 0; f < 4; ++f) acc += dot4(sTF4[bi*5 + f], zHn[f]);
                sV[bi*4 + bm] = acc;
            }
            if (tid < 16) {
                float acc = zR;
#pragma unroll
                for (int f = 0; f < 4; ++f) acc += dot4(sHP4[(tid >> 2)*4 + f], zHn[f]);
                sS[tid] = acc;
            }
            __syncthreads();

            // s3: B = V * S^{-1} via cofactors
            {
                int ra = (bm == 0) ? 1 : 0;
                int rb = (bm <= 1) ? 2 : 1;
                int rc = (bm <= 2) ? 3 : 2;
                float4 a = sS4[ra], b = sS4[rb], c = sS4[rc], sm = sS4[bm];
                float M0 = a.y*(b.z*c.w - b.w*c.z) - a.z*(b.y*c.w - b.w*c.y) + a.w*(b.y*c.z - b.z*c.y);
                float M1 = a.x*(b.z*c.w - b.w*c.z) - a.z*(b.x*c.w - b.w*c.x) + a.w*(b.x*c.z - b.z*c.x);
                float M2 = a.x*(b.y*c.w - b.w*c.y) - a.y*(b.x*c.w - b.w*c.x) + a.w*(b.x*c.y - b.y*c.x);
                float M3 = a.x*(b.y*c.z - b.z*c.y) - a.y*(b.x*c.z - b.z*c.x) + a.z*(b.x*c.y - b.y*c.x);
                float sg = (bm & 1) ? -1.f : 1.f;
                float c0 = sg*M0, c1 = -sg*M1, c2 = sg*M2, c3 = -sg*M3;
                float det = sm.x*c0 + sm.y*c1 + sm.z*c2 + sm.w*c3;
                float4 vv = sV4[bi];
                float bval = (vv.x*c0 + vv.y*c1 + vv.z*c2 + vv.w*c3) / det;
                sB[tid] = bval;
                sABf[ssb*320 + 256 + tid] = bval;
            }
            __syncthreads();

            // s4: A = F - B*H, AP = TF - B*HP, RBt = R*B^T
            {
                float h0 = sH[j],  h1 = sH[16 + j],  h2 = sH[32 + j],  h3 = sH[48 + j];
                float p0 = sHP[j], p1 = sHP[16 + j], p2 = sHP[32 + j], p3 = sHP[48 + j];
#pragma unroll
                for (int r = 0; r < 4; ++r) {
                    int i = q + 4*r;
                    float4 bb = sB4[i];
                    float av = sF[i*20 + j] - (bb.x*h0 + bb.y*h1 + bb.z*h2 + bb.w*h3);
                    aval[r] = av;
                    sA[i*20 + j] = av;
                    sABf[ssb*320 + i*16 + j] = av;
                    sAP[i*20 + j] = tf[r] - (bb.x*p0 + bb.y*p1 + bb.z*p2 + bb.w*p3);
                }
                sRBt[q*16 + j] = dot4(zRq, sB4[j]);
            }
            __syncthreads();

            // s5: P' = AP*A^T + B*RBt + Q, conv check
            float4 zA[4];
#pragma unroll
            for (int f = 0; f < 4; ++f) zA[f] = sA4p[j*5 + f];
            float rb0 = sRBt[j], rb1 = sRBt[16 + j], rb2 = sRBt[32 + j], rb3 = sRBt[48 + j];
            float dmax = 0.f;
#pragma unroll
            for (int r = 0; r < 4; ++r) {
                int i = q + 4*r;
                float4 bb = sB4[i];
                float acc = zQ[r] + bb.x*rb0 + bb.y*rb1 + bb.z*rb2 + bb.w*rb3;
#pragma unroll
                for (int f = 0; f < 4; ++f) acc += dot4(sAP4[i*5 + f], zA[f]);
                float po = sP[i*20 + j];
                sP[i*20 + j] = acc;
                dmax = fmaxf(dmax, fabsf(acc - po));
            }
            __syncthreads();

            bool conv = (t >= 32) && __all(dmax < CONV_EPS);
            if (ssb == 15 || conv || t == NSTEP - 1) {
                int cb = t & ~15, nf = ssb + 1;
                for (int ss = 0; ss < nf; ++ss) {
                    float4* dst = wsf4 + (cb + ss)*80;
                    const float4* src = sABbuf4 + ss*80;
                    dst[tid] = src[tid];
                    if (tid < 16) dst[64 + tid] = src[64 + tid];
                }
                // publish only COMPLETE chunks (conv mid-chunk -> fill first)
                if ((ssb == 15 || t == NSTEP - 1) && tid == 0)
                    __hip_atomic_store(flagp, (t >> 4) + 1,
                                       __ATOMIC_RELEASE, __HIP_MEMORY_SCOPE_AGENT);
            }
            if (conv) { ++t; break; }
        }

        // fill remaining steps with converged A/B, then publish everything
        if (t < NSTEP) {
#pragma unroll
            for (int r = 0; r < 4; ++r) sTF[(q + 4*r)*16 + j] = aval[r];
            __syncthreads();
            float4 fa = ((float4*)sTF)[tid];
            float4 fb = sB4[tid & 15];
            for (int tt = t; tt < NSTEP; ++tt) {
                wsf4[tt*80 + tid] = fa;
                if (tid < 16) wsf4[tt*80 + 64 + tid] = fb;
            }
            if (tid == 0)
                __hip_atomic_store(flagp, NCHUNK,
                                   __ATOMIC_RELEASE, __HIP_MEMORY_SCOPE_AGENT);
        }
        return;
    }

    // =================== CONSUMERS: batched filter ===================
    const int g = tid >> 4;           // batch group 0..3
    const int i = tid & 15;           // state index
    const int gbase = tid & 48;       // first lane of this group
    const int b = (blockIdx.x - 1) * 4 + g;

    // H row (i&3) as 16 scalars in regs (used by lanes i<4 for output)
    const float4* Hg4c = (const float4*)Hg;
    float4 h0 = Hg4c[(i & 3)*4 + 0], h1 = Hg4c[(i & 3)*4 + 1],
           h2 = Hg4c[(i & 3)*4 + 2], h3 = Hg4c[(i & 3)*4 + 3];
    float hr[16] = {h0.x,h0.y,h0.z,h0.w, h1.x,h1.y,h1.z,h1.w,
                    h2.x,h2.y,h2.z,h2.w, h3.x,h3.y,h3.z,h3.w};

    const float4* wsf4 = (const float4*)ws;
    const float4* obs4 = (const float4*)obs;

    // wait for chunk 0 (also guarantees z0 visibility)
    while (__hip_atomic_load(flagp, __ATOMIC_ACQUIRE, __HIP_MEMORY_SCOPE_AGENT) < 1)
        __builtin_amdgcn_s_sleep(2);
    float zr = ws[Z0_OFF + i];        // lane (g,i) holds z_i for batch b

    for (int k = 0; k < NCHUNK; ++k) {
        const int len = (k == NCHUNK - 1) ? (NSTEP - 16*(NCHUNK - 1)) : 16;
        if (k > 0) {
            while (__hip_atomic_load(flagp, __ATOMIC_ACQUIRE, __HIP_MEMORY_SCOPE_AGENT) < k + 1)
                __builtin_amdgcn_s_sleep(2);
        }
        __syncthreads();   // reuse guard for sA (single wave: waitcnt only)
        // stage A rows (restride 16 -> 20: conflict-free b128 reads)
        for (int u = tid; u < len * 64; u += 64) {
            int ss = u >> 6, rem = u & 63, row = rem >> 2, f = rem & 3;
            sA4[ss*80 + row*5 + f] = wsf4[(k*16 + ss)*80 + rem];
        }
        for (int u = tid; u < len * 16; u += 64) {
            int ss = u >> 4, r2 = u & 15;
            sB4v[ss*16 + r2] = wsf4[(k*16 + ss)*80 + 64 + r2];
        }
        {
            int ss = tid & 15, gg = tid >> 4;
            if (ss < len)
                sObs4[gg*16 + ss] = obs4[((blockIdx.x - 1)*4 + gg) * NT + k*16 + ss];
        }
        __syncthreads();
        for (int ss = 0; ss < len; ++ss) {
            const int t = k*16 + ss;
            float4 a0 = sA4[ss*80 + i*5 + 0], a1 = sA4[ss*80 + i*5 + 1],
                   a2 = sA4[ss*80 + i*5 + 2], a3 = sA4[ss*80 + i*5 + 3];
            float ar[16] = {a0.x,a0.y,a0.z,a0.w, a1.x,a1.y,a1.z,a1.w,
                            a2.x,a2.y,a2.z,a2.w, a3.x,a3.y,a3.z,a3.w};
            float4 bb = sB4v[ss*16 + i];
            float4 oo = sObs4[g*16 + ss];
            float zn = dot4(bb, oo);
            float o  = 0.f;
#pragma unroll
            for (int jj = 0; jj < 16; ++jj) {
                float zj = __shfl(zr, gbase + jj);   // broadcast z_t[jj]
                zn = fmaf(ar[jj], zj, zn);           // A z_t
                o  = fmaf(hr[jj], zj, o);            // H z_t -> out time t
            }
            if (i < 4) out[b * (NT*4) + t*4 + i] = o;
            zr = zn;                                  // no LDS, no barrier
        }
    }
    // final output: time 255 = H z_255
    {
        float o = 0.f;
#pragma unroll
        for (int jj = 0; jj < 16; ++jj) {
            float zj = __shfl(zr, gbase + jj);
            o = fmaf(hr[jj], zj, o);
        }
        if (i < 4) out[b * (NT*4) + 255*4 + i] = o;
    }
}

extern "C" void kernel_launch(void* const* d_in, const int* in_sizes, int n_in,
                              void* d_out, int out_size, void* d_ws, size_t ws_size,
                              hipStream_t stream) {
    const float* obs = (const float*)d_in[0];   // [B,T,M]
    const float* F   = (const float*)d_in[1];   // [S,S]
    const float* H   = (const float*)d_in[2];   // [M,S]
    const float* Q   = (const float*)d_in[3];   // [S,S]
    const float* R   = (const float*)d_in[4];   // [M,M]
    const float* x0  = (const float*)d_in[5];   // [S]
    const float* sd  = (const float*)d_in[6];   // [S]
    float* ws  = (float*)d_ws;
    float* out = (float*)d_out;

    hipLaunchKernelGGL(kf_fused_kernel, dim3(257), dim3(64), 0, stream,
                       obs, F, H, Q, R, x0, sd, ws, out);
}

// Round 8
// 347.543 us; speedup vs baseline: 1.7368x; 1.0465x over previous
//
#include <hip/hip_runtime.h>

// B=1024 groups, T=256 steps, S=16 states, M=4 measurements
#define NT 256
#define NSTEP 255
#define AB_STRIDE 320                 // 256 (A row-major) + 64 (B) floats per step
#define Z0_OFF (NSTEP * AB_STRIDE)    // 81600
#define OUT0_OFF (Z0_OFF + 16)        // 81616
#define FLAG_OFF 81632                // int flag (ws poison 0xAA -> negative)
#define CONV_EPS 1e-4f
#define NCHUNK 16

__device__ __forceinline__ float dot4(float4 a, float4 b) {
    return a.x*b.x + a.y*b.y + a.z*b.z + a.w*b.w;
}

// -----------------------------------------------------------------------------
// Fused producer/consumer pipeline, 129 blocks x 64 threads (1 block/CU).
// Block 0 (producer): shared Riccati, Joseph form, single wave, 5 LDS stages
//   per step; publishes 16-step (A|B) chunks to ws + monotone agent flag.
// Blocks 1..128 (consumers): 8 batches each, 8 lanes/batch, z in float2 regs.
//   Poll flag with RELAXED loads + one __threadfence() on exit (no per-poll
//   L1 invalidate — R6's per-poll acquire degraded the producer 198->320us).
//   Inner step: 8 conflict-free ds_read_b128 + 16 shfl + ~48 FMA, no barrier.
// R8 fix: obs staging loop for partial chunks covered only u<len*8 of the
//   (gg=u>>4, ss=u&15) index space, silently skipping gg=7/ss>=8 on the last
//   chunk (stale obs -> absmax 3.59). Now iterates the full 128-slot space
//   with the ss<len guard.
// -----------------------------------------------------------------------------
__global__ __launch_bounds__(64) void kf_fused_kernel(
    const float* __restrict__ obs, const float* __restrict__ Fg,
    const float* __restrict__ Hg,  const float* __restrict__ Qg,
    const float* __restrict__ Rg,  const float* __restrict__ x0g,
    const float* __restrict__ sdg, float* __restrict__ ws,
    float* __restrict__ out)
{
    // ---- producer LDS ----
    __shared__ float4 sF4[80], sP4[80], sTF4[80], sA4p[80], sAP4[80];
    __shared__ float4 sHP4[16], sRBt4[16], sS4[4], sV4[16], sB4[16];
    __shared__ float  sH[64];
    __shared__ float4 sABbuf4[16 * 80];   // 16-step chunk of (A|B) = 20 KB
    // ---- consumer LDS ----
    __shared__ float4 sA4[16 * 80];       // staged A rows, stride 20 = 20 KB
    __shared__ float4 sB4v[16 * 16];
    __shared__ float4 sObs4[8 * 16];      // [g][ss]

    const int tid = threadIdx.x;
    int* flagp = (int*)ws + FLAG_OFF;

    if (blockIdx.x == 0) {
        // =================== PRODUCER: Riccati ===================
        float* sF   = (float*)sF4;   float* sP   = (float*)sP4;
        float* sTF  = (float*)sTF4;  float* sA   = (float*)sA4p;
        float* sAP  = (float*)sAP4;  float* sV   = (float*)sV4;
        float* sS   = (float*)sS4;   float* sHP  = (float*)sHP4;
        float* sRBt = (float*)sRBt4; float* sB   = (float*)sB4;
        float* sABf = (float*)sABbuf4;

        const int q  = tid >> 4;     // row quad
        const int j  = tid & 15;     // column
        const int bi = tid >> 2;     // B row
        const int bm = tid & 3;      // B col / S row

        const float4* Fg4 = (const float4*)Fg;
        const float4* Hg4 = (const float4*)Hg;
        const float4* Rg4 = (const float4*)Rg;
        float4* wsf4 = (float4*)ws;

        for (int u = tid; u < 256; u += 64) sF[(u >> 4) * 20 + (u & 15)] = Fg[u];
        sH[tid] = Hg[tid];

        float4 zF[4][4], zFj[4], zHq[4], zHn[4];
#pragma unroll
        for (int r = 0; r < 4; ++r)
#pragma unroll
            for (int f = 0; f < 4; ++f) zF[r][f] = Fg4[(q + 4*r)*4 + f];
#pragma unroll
        for (int f = 0; f < 4; ++f) {
            zFj[f] = Fg4[j*4 + f];
            zHq[f] = Hg4[q*4 + f];
            zHn[f] = Hg4[bm*4 + f];
        }
        float zQ[4];
#pragma unroll
        for (int r = 0; r < 4; ++r) zQ[r] = Qg[(q + 4*r)*16 + j];
        float  zR  = Rg[tid & 15];
        float4 zRq = Rg4[q];
        float4 zSd2[4];
#pragma unroll
        for (int f = 0; f < 4; ++f) {
            float4 s = ((const float4*)sdg)[f];
            zSd2[f] = make_float4(s.x*s.x, s.y*s.y, s.z*s.z, s.w*s.w);
        }
        __syncthreads();

        // P = F diag(sd^2) F^T + Q
#pragma unroll
        for (int r = 0; r < 4; ++r) {
            float acc = zQ[r];
#pragma unroll
            for (int f = 0; f < 4; ++f) {
                float4 a = zF[r][f], b = zFj[f], s = zSd2[f];
                acc += a.x*s.x*b.x + a.y*s.y*b.y + a.z*s.z*b.z + a.w*s.w*b.w;
            }
            sP[(q + 4*r)*20 + j] = acc;
        }
        // z0 = F x0, out0 = H z0
        if (tid < 16) {
            float acc = 0.f;
#pragma unroll
            for (int f = 0; f < 4; ++f) {
                float4 fr = ((float4*)(sF + tid*20))[f];
                float4 xv = ((const float4*)x0g)[f];
                acc += dot4(fr, xv);
            }
            sV[tid] = acc;
            ws[Z0_OFF + tid] = acc;
        }
        __syncthreads();
        if (tid < 4) {
            float acc = 0.f;
#pragma unroll
            for (int k = 0; k < 16; ++k) acc += sH[tid*16 + k] * sV[k];
            ws[OUT0_OFF + tid] = acc;
        }
        __syncthreads();

        float aval[4] = {0.f, 0.f, 0.f, 0.f};
        int t;
        for (t = 0; t < NSTEP; ++t) {
            const int ssb = t & 15;
            // s1: TF = F*P, HP = H*P
            float4 zP[4];
#pragma unroll
            for (int f = 0; f < 4; ++f) zP[f] = sP4[j*5 + f];
            float tf[4], hp = 0.f;
#pragma unroll
            for (int r = 0; r < 4; ++r) {
                float acc = 0.f;
#pragma unroll
                for (int f = 0; f < 4; ++f) acc += dot4(zF[r][f], zP[f]);
                tf[r] = acc;
            }
#pragma unroll
            for (int f = 0; f < 4; ++f) hp += dot4(zHq[f], zP[f]);
#pragma unroll
            for (int r = 0; r < 4; ++r) sTF[(q + 4*r)*20 + j] = tf[r];
            sHP[q*16 + j] = hp;
            __syncthreads();

            // s2: V = TF*H^T, S = HP*H^T + R
            {
                float acc = 0.f;
#pragma unroll
                for (int f = 0; f < 4; ++f) acc += dot4(sTF4[bi*5 + f], zHn[f]);
                sV[bi*4 + bm] = acc;
            }
            if (tid < 16) {
                float acc = zR;
#pragma unroll
                for (int f = 0; f < 4; ++f) acc += dot4(sHP4[(tid >> 2)*4 + f], zHn[f]);
                sS[tid] = acc;
            }
            __syncthreads();

            // s3: B = V * S^{-1} via cofactors
            {
                int ra = (bm == 0) ? 1 : 0;
                int rb = (bm <= 1) ? 2 : 1;
                int rc = (bm <= 2) ? 3 : 2;
                float4 a = sS4[ra], b = sS4[rb], c = sS4[rc], sm = sS4[bm];
                float M0 = a.y*(b.z*c.w - b.w*c.z) - a.z*(b.y*c.w - b.w*c.y) + a.w*(b.y*c.z - b.z*c.y);
                float M1 = a.x*(b.z*c.w - b.w*c.z) - a.z*(b.x*c.w - b.w*c.x) + a.w*(b.x*c.z - b.z*c.x);
                float M2 = a.x*(b.y*c.w - b.w*c.y) - a.y*(b.x*c.w - b.w*c.x) + a.w*(b.x*c.y - b.y*c.x);
                float M3 = a.x*(b.y*c.z - b.z*c.y) - a.y*(b.x*c.z - b.z*c.x) + a.z*(b.x*c.y - b.y*c.x);
                float sg = (bm & 1) ? -1.f : 1.f;
                float c0 = sg*M0, c1 = -sg*M1, c2 = sg*M2, c3 = -sg*M3;
                float det = sm.x*c0 + sm.y*c1 + sm.z*c2 + sm.w*c3;
                float4 vv = sV4[bi];
                float bval = (vv.x*c0 + vv.y*c1 + vv.z*c2 + vv.w*c3) / det;
                sB[tid] = bval;
                sABf[ssb*320 + 256 + tid] = bval;
            }
            __syncthreads();

            // s4: A = F - B*H, AP = TF - B*HP, RBt = R*B^T
            {
                float h0 = sH[j],  h1 = sH[16 + j],  h2 = sH[32 + j],  h3 = sH[48 + j];
                float p0 = sHP[j], p1 = sHP[16 + j], p2 = sHP[32 + j], p3 = sHP[48 + j];
#pragma unroll
                for (int r = 0; r < 4; ++r) {
                    int i = q + 4*r;
                    float4 bb = sB4[i];
                    float av = sF[i*20 + j] - (bb.x*h0 + bb.y*h1 + bb.z*h2 + bb.w*h3);
                    aval[r] = av;
                    sA[i*20 + j] = av;
                    sABf[ssb*320 + i*16 + j] = av;
                    sAP[i*20 + j] = tf[r] - (bb.x*p0 + bb.y*p1 + bb.z*p2 + bb.w*p3);
                }
                sRBt[q*16 + j] = dot4(zRq, sB4[j]);
            }
            __syncthreads();

            // s5: P' = AP*A^T + B*RBt + Q, conv check
            float4 zA[4];
#pragma unroll
            for (int f = 0; f < 4; ++f) zA[f] = sA4p[j*5 + f];
            float rb0 = sRBt[j], rb1 = sRBt[16 + j], rb2 = sRBt[32 + j], rb3 = sRBt[48 + j];
            float dmax = 0.f;
#pragma unroll
            for (int r = 0; r < 4; ++r) {
                int i = q + 4*r;
                float4 bb = sB4[i];
                float acc = zQ[r] + bb.x*rb0 + bb.y*rb1 + bb.z*rb2 + bb.w*rb3;
#pragma unroll
                for (int f = 0; f < 4; ++f) acc += dot4(sAP4[i*5 + f], zA[f]);
                float po = sP[i*20 + j];
                sP[i*20 + j] = acc;
                dmax = fmaxf(dmax, fabsf(acc - po));
            }
            __syncthreads();

            bool conv = (t >= 32) && __all(dmax < CONV_EPS);
            if (ssb == 15 || conv || t == NSTEP - 1) {
                int cb = t & ~15, nf = ssb + 1;
                for (int ss = 0; ss < nf; ++ss) {
                    float4* dst = wsf4 + (cb + ss)*80;
                    const float4* src = sABbuf4 + ss*80;
                    dst[tid] = src[tid];
                    if (tid < 16) dst[64 + tid] = src[64 + tid];
                }
                // publish only COMPLETE chunks (conv mid-chunk -> fill first)
                if ((ssb == 15 || t == NSTEP - 1) && tid == 0)
                    __hip_atomic_store(flagp, (t >> 4) + 1,
                                       __ATOMIC_RELEASE, __HIP_MEMORY_SCOPE_AGENT);
            }
            if (conv) { ++t; break; }
        }

        // fill remaining steps with converged A/B, then publish everything
        if (t < NSTEP) {
#pragma unroll
            for (int r = 0; r < 4; ++r) sTF[(q + 4*r)*16 + j] = aval[r];
            __syncthreads();
            float4 fa = ((float4*)sTF)[tid];
            float4 fb = sB4[tid & 15];
            for (int tt = t; tt < NSTEP; ++tt) {
                wsf4[tt*80 + tid] = fa;
                if (tid < 16) wsf4[tt*80 + 64 + tid] = fb;
            }
            if (tid == 0)
                __hip_atomic_store(flagp, NCHUNK,
                                   __ATOMIC_RELEASE, __HIP_MEMORY_SCOPE_AGENT);
        }
        return;
    }

    // =================== CONSUMERS: batched filter ===================
    // 8 batches/block, 8 lanes/batch; lane l of group g holds z[l], z[l+8].
    const int g = tid >> 3;           // batch group 0..7
    const int l = tid & 7;            // state-pair index (rows l and l+8)
    const int gbase = tid & 56;       // first lane of this group
    const int b = (blockIdx.x - 1) * 8 + g;

    // H row (l&3) as 16 scalars in regs (used by lanes l<4 for output)
    const float4* Hg4c = (const float4*)Hg;
    float4 h0 = Hg4c[(l & 3)*4 + 0], h1 = Hg4c[(l & 3)*4 + 1],
           h2 = Hg4c[(l & 3)*4 + 2], h3 = Hg4c[(l & 3)*4 + 3];
    float hr[16] = {h0.x,h0.y,h0.z,h0.w, h1.x,h1.y,h1.z,h1.w,
                    h2.x,h2.y,h2.z,h2.w, h3.x,h3.y,h3.z,h3.w};

    const float4* wsf4 = (const float4*)ws;
    const float4* obs4 = (const float4*)obs;

    // wait for chunk 0 (relaxed poll; fence gives acquire ordering once)
    while (__hip_atomic_load(flagp, __ATOMIC_RELAXED, __HIP_MEMORY_SCOPE_AGENT) < 1)
        __builtin_amdgcn_s_sleep(8);
    __threadfence();
    float zlo = ws[Z0_OFF + l], zhi = ws[Z0_OFF + l + 8];

    for (int k = 0; k < NCHUNK; ++k) {
        const int len = (k == NCHUNK - 1) ? (NSTEP - 16*(NCHUNK - 1)) : 16;
        if (k > 0) {
            while (__hip_atomic_load(flagp, __ATOMIC_RELAXED, __HIP_MEMORY_SCOPE_AGENT) < k + 1)
                __builtin_amdgcn_s_sleep(8);
            __threadfence();
        }
        __syncthreads();   // single-wave: waitcnt-only reuse guard for sA
        // stage A rows (restride 16 -> 20: conflict-free b128 reads)
        for (int u = tid; u < len * 64; u += 64) {
            int ss = u >> 6, rem = u & 63, row = rem >> 2, f = rem & 3;
            sA4[ss*80 + row*5 + f] = wsf4[(k*16 + ss)*80 + rem];
        }
        for (int u = tid; u < len * 16; u += 64) {
            int ss = u >> 4, r2 = u & 15;
            sB4v[ss*16 + r2] = wsf4[(k*16 + ss)*80 + 64 + r2];
        }
        // obs staging: full 128-slot (gg,ss) space with ss<len guard.
        // (R7 bug: bound len*8 skipped gg=7/ss>=8 on the last chunk.)
        for (int u = tid; u < 128; u += 64) {
            int ss = u & 15, gg = u >> 4;
            if (ss < len)
                sObs4[gg*16 + ss] = obs4[((blockIdx.x - 1)*8 + gg) * NT + k*16 + ss];
        }
        __syncthreads();
        for (int ss = 0; ss < len; ++ss) {
            const int t = k*16 + ss;
            float4 a0 = sA4[ss*80 + l*5 + 0], a1 = sA4[ss*80 + l*5 + 1],
                   a2 = sA4[ss*80 + l*5 + 2], a3 = sA4[ss*80 + l*5 + 3];
            float4 a4 = sA4[ss*80 + (l+8)*5 + 0], a5 = sA4[ss*80 + (l+8)*5 + 1],
                   a6 = sA4[ss*80 + (l+8)*5 + 2], a7 = sA4[ss*80 + (l+8)*5 + 3];
            float alo[16] = {a0.x,a0.y,a0.z,a0.w, a1.x,a1.y,a1.z,a1.w,
                             a2.x,a2.y,a2.z,a2.w, a3.x,a3.y,a3.z,a3.w};
            float ahi[16] = {a4.x,a4.y,a4.z,a4.w, a5.x,a5.y,a5.z,a5.w,
                             a6.x,a6.y,a6.z,a6.w, a7.x,a7.y,a7.z,a7.w};
            float4 blo = sB4v[ss*16 + l], bhi = sB4v[ss*16 + l + 8];
            float4 oo  = sObs4[g*16 + ss];
            float znlo = dot4(blo, oo);
            float znhi = dot4(bhi, oo);
            float o    = 0.f;
#pragma unroll
            for (int jj = 0; jj < 16; ++jj) {
                float zj = (jj < 8) ? __shfl(zlo, gbase + jj)
                                    : __shfl(zhi, gbase + jj - 8);
                znlo = fmaf(alo[jj], zj, znlo);      // (A z)[l]
                znhi = fmaf(ahi[jj], zj, znhi);      // (A z)[l+8]
                o    = fmaf(hr[jj],  zj, o);         // (H z)[l] -> out time t
            }
            if (l < 4) out[b * (NT*4) + t*4 + l] = o;
            zlo = znlo; zhi = znhi;                  // no LDS, no barrier
        }
    }
    // final output: time 255 = H z_255
    {
        float o = 0.f;
#pragma unroll
        for (int jj = 0; jj < 16; ++jj) {
            float zj = (jj < 8) ? __shfl(zlo, gbase + jj)
                                : __shfl(zhi, gbase + jj - 8);
            o = fmaf(hr[jj], zj, o);
        }
        if (l < 4) out[b * (NT*4) + 255*4 + l] = o;
    }
}

extern "C" void kernel_launch(void* const* d_in, const int* in_sizes, int n_in,
                              void* d_out, int out_size, void* d_ws, size_t ws_size,
                              hipStream_t stream) {
    const float* obs = (const float*)d_in[0];   // [B,T,M]
    const float* F   = (const float*)d_in[1];   // [S,S]
    const float* H   = (const float*)d_in[2];   // [M,S]
    const float* Q   = (const float*)d_in[3];   // [S,S]
    const float* R   = (const float*)d_in[4];   // [M,M]
    const float* x0  = (const float*)d_in[5];   // [S]
    const float* sd  = (const float*)d_in[6];   // [S]
    float* ws  = (float*)d_ws;
    float* out = (float*)d_out;

    hipLaunchKernelGGL(kf_fused_kernel, dim3(129), dim3(64), 0, stream,
                       obs, F, H, Q, R, x0, sd, ws, out);
}

// Round 9
// 242.117 us; speedup vs baseline: 2.4931x; 1.4354x over previous
//
#include <hip/hip_runtime.h>

// B=1024 groups, T=256 steps, S=16 states, M=4 measurements
#define NT 256
#define NSTEP 255
#define CONV_EPS 2.5e-4f   // steady-state |dP| jitter measured >=1e-4 (R5/R8); 2.5e-4 sits above it
#define CONV_TMIN 48       // 0.8^48~2e-5: by t=48 genuine decay is below eps -> freeze error ~1e-3

__device__ __forceinline__ float dot4(float4 a, float4 b) {
    return a.x*b.x + a.y*b.y + a.z*b.z + a.w*b.w;
}

// -----------------------------------------------------------------------------
// R9: fully decoupled. 256 blocks x 64 threads (1 wave, 1 block/CU). Each block
// REDUNDANTLY runs the shared Riccati recursion (Joseph form, R5's proven
// 5-stage structure) and, fused into stage 5 of the same wave, applies the
// just-computed A_t/B_t to its own 4 batches (z in regs, 16 lanes/batch,
// broadcast via __shfl). No flags, no ws, no cross-block traffic at all —
// R6/R8 showed any producer->consumer signaling degrades the producer.
// obs staged once into LDS (16 KB); out accumulated in LDS, flushed at end.
// Conv-freeze: when max|dP| < 2.5e-4 (t>=48), A/B/H move to registers and the
// remaining steps run a barrier-free shfl+FMA loop (~130 cyc/step).
// -----------------------------------------------------------------------------
__global__ __launch_bounds__(64) void kf_block_kernel(
    const float* __restrict__ obs, const float* __restrict__ Fg,
    const float* __restrict__ Hg,  const float* __restrict__ Qg,
    const float* __restrict__ Rg,  const float* __restrict__ x0g,
    const float* __restrict__ sdg, float* __restrict__ out)
{
    __shared__ float4 sF4[80];     // F, row stride 20 floats
    __shared__ float4 sP4[80];     // P, stride 20
    __shared__ float4 sA4[80];     // A, stride 20
    __shared__ float4 sAP4[80];    // AP = A*P, stride 20
    __shared__ float4 sHP4[16];    // HP [m][s]
    __shared__ float4 sV4[16];     // V [i][m]
    __shared__ float4 sB4[16];     // B [i][m]
    __shared__ float4 sS4[4];      // S 4x4
    __shared__ float  sH[64];      // H [m][s]
    __shared__ float  sZ[16];      // z0
    __shared__ float4 sObs4[1024]; // [g][t] observation float4, 16 KB
    __shared__ float4 sOut4[1024]; // [g][t] output float4, 16 KB

    float* sF  = (float*)sF4;
    float* sP  = (float*)sP4;
    float* sA  = (float*)sA4;
    float* sAP = (float*)sAP4;
    float* sHP = (float*)sHP4;
    float* sV  = (float*)sV4;
    float* sB  = (float*)sB4;
    float* sS  = (float*)sS4;
    float* sOut = (float*)sOut4;

    const int tid = threadIdx.x;
    const int q  = tid >> 4;      // row quad 0..3  (also: filter batch group g)
    const int j  = tid & 15;      // column 0..15   (also: filter state index i)
    const int bi = tid >> 2;      // B row 0..15
    const int bm = tid & 3;       // B col / S row 0..3
    const int gbase = tid & 48;   // first lane of this 16-lane group

    const float4* Fg4 = (const float4*)Fg;
    const float4* Hg4 = (const float4*)Hg;
    const float4* Rg4 = (const float4*)Rg;
    const float4* obs4g = (const float4*)obs;

    // ---- stage constants into LDS ----
    for (int u = tid; u < 256; u += 64) sF[(u >> 4) * 20 + (u & 15)] = Fg[u];
    sH[tid] = Hg[tid];
    // obs for this block's 4 batches: [g][t], coalesced 64-float4 runs
    for (int u = tid; u < 1024; u += 64)
        sObs4[u] = obs4g[(blockIdx.x * 4 + (u >> 8)) * NT + (u & 255)];

    // ---- per-lane register preloads ----
    float4 zF[4][4], zFbi[4], zFj[4], zHq[4], zHn[4], zHrow4[4];
#pragma unroll
    for (int r = 0; r < 4; ++r)
#pragma unroll
        for (int f = 0; f < 4; ++f) zF[r][f] = Fg4[(q + 4*r)*4 + f];
#pragma unroll
    for (int f = 0; f < 4; ++f) {
        zFbi[f]   = Fg4[bi*4 + f];        // F row bi   (V stage)
        zFj[f]    = Fg4[j*4 + f];         // F row j    (init only)
        zHq[f]    = Hg4[q*4 + f];         // H row q    (HP stage)
        zHn[f]    = Hg4[bm*4 + f];        // H row bm   (S stage)
        zHrow4[f] = Hg4[(j & 3)*4 + f];   // H row (j&3) (filter output)
    }
    float hr[16] = {zHrow4[0].x,zHrow4[0].y,zHrow4[0].z,zHrow4[0].w,
                    zHrow4[1].x,zHrow4[1].y,zHrow4[1].z,zHrow4[1].w,
                    zHrow4[2].x,zHrow4[2].y,zHrow4[2].z,zHrow4[2].w,
                    zHrow4[3].x,zHrow4[3].y,zHrow4[3].z,zHrow4[3].w};
    float zQ[4];
#pragma unroll
    for (int r = 0; r < 4; ++r) zQ[r] = Qg[(q + 4*r)*16 + j];
    float  zRs = Rg[tid & 15];            // R[m][n] for S stage (tid<16)
    float4 zR4[4];
#pragma unroll
    for (int m = 0; m < 4; ++m) zR4[m] = Rg4[m];
    float4 zHcjv = make_float4(Hg[j], Hg[16 + j], Hg[32 + j], Hg[48 + j]); // H col j
    float4 zFijv = make_float4(Fg[q*16 + j],      Fg[(q+4)*16 + j],
                               Fg[(q+8)*16 + j],  Fg[(q+12)*16 + j]);     // F[q+4r][j]
    float4 zSd2[4];
#pragma unroll
    for (int f = 0; f < 4; ++f) {
        float4 s = ((const float4*)sdg)[f];
        zSd2[f] = make_float4(s.x*s.x, s.y*s.y, s.z*s.z, s.w*s.w);
    }
    __syncthreads();   // sF, sH, sObs ready

    // ---- P0 = F diag(sd^2) F^T + Q ----
#pragma unroll
    for (int r = 0; r < 4; ++r) {
        float acc = zQ[r];
#pragma unroll
        for (int f = 0; f < 4; ++f) {
            float4 a = zF[r][f], b = zFj[f], s = zSd2[f];
            acc += a.x*s.x*b.x + a.y*s.y*b.y + a.z*s.z*b.z + a.w*s.w*b.w;
        }
        sP[(q + 4*r)*20 + j] = acc;
    }
    // ---- z0 = F x0 ----
    if (tid < 16) {
        float acc = 0.f;
#pragma unroll
        for (int f = 0; f < 4; ++f) {
            float4 fr = ((float4*)(sF + tid*20))[f];
            float4 xv = ((const float4*)x0g)[f];
            acc += dot4(fr, xv);
        }
        sZ[tid] = acc;
    }
    __syncthreads();
    float zr = sZ[j];    // lane (g=q, i=j) holds z_i for batch blockIdx*4+g

    float arF[16];       // frozen A row i
    float4 bbF;          // frozen B row i
    bool frozen = false;
    int t;
    for (t = 0; t < NSTEP; ++t) {
        // ---- s1: TF rows (regs), HP row q ----
        float4 zP[4];
#pragma unroll
        for (int f = 0; f < 4; ++f) zP[f] = sP4[j*5 + f];
        float tf[4], hp = 0.f;
#pragma unroll
        for (int r = 0; r < 4; ++r) {
            float acc = 0.f;
#pragma unroll
            for (int f = 0; f < 4; ++f) acc += dot4(zF[r][f], zP[f]);
            tf[r] = acc;
        }
#pragma unroll
        for (int f = 0; f < 4; ++f) hp += dot4(zHq[f], zP[f]);
        sHP[q*16 + j] = hp;
        __syncthreads();

        // ---- s2: V[bi][bm] = F_bi . HP_bm (P sym), S = HP*H^T + R ----
        {
            float acc = 0.f;
#pragma unroll
            for (int f = 0; f < 4; ++f) acc += dot4(zFbi[f], sHP4[bm*4 + f]);
            sV[bi*4 + bm] = acc;
        }
        if (tid < 16) {
            float acc = zRs;
#pragma unroll
            for (int f = 0; f < 4; ++f) acc += dot4(sHP4[(tid >> 2)*4 + f], zHn[f]);
            sS[tid] = acc;
        }
        __syncthreads();

        // ---- s3: B[bi][bm] via cofactors of S row bm ----
        {
            int ra = (bm == 0) ? 1 : 0;
            int rb = (bm <= 1) ? 2 : 1;
            int rc = (bm <= 2) ? 3 : 2;
            float4 a = sS4[ra], b = sS4[rb], c = sS4[rc], sm = sS4[bm];
            float M0 = a.y*(b.z*c.w - b.w*c.z) - a.z*(b.y*c.w - b.w*c.y) + a.w*(b.y*c.z - b.z*c.y);
            float M1 = a.x*(b.z*c.w - b.w*c.z) - a.z*(b.x*c.w - b.w*c.x) + a.w*(b.x*c.z - b.z*c.x);
            float M2 = a.x*(b.y*c.w - b.w*c.y) - a.y*(b.x*c.w - b.w*c.x) + a.w*(b.x*c.y - b.y*c.x);
            float M3 = a.x*(b.y*c.z - b.z*c.y) - a.y*(b.x*c.z - b.z*c.x) + a.z*(b.x*c.y - b.y*c.x);
            float sg = (bm & 1) ? -1.f : 1.f;
            float c0 = sg*M0, c1 = -sg*M1, c2 = sg*M2, c3 = -sg*M3;
            float det = sm.x*c0 + sm.y*c1 + sm.z*c2 + sm.w*c3;
            float4 vv = sV4[bi];
            sB[tid] = (vv.x*c0 + vv.y*c1 + vv.z*c2 + vv.w*c3) / det;
        }
        __syncthreads();

        // ---- s4: A = F - B*H, AP = TF - B*HP (rows q+4r); rbt = R * Brow_j ----
        float4 bq[4], rbtv;
        {
            float4 hpcv = make_float4(sHP[j], sHP[16 + j], sHP[32 + j], sHP[48 + j]);
            float4 bj = sB4[j];
#pragma unroll
            for (int r = 0; r < 4; ++r) {
                int i = q + 4*r;
                bq[r] = sB4[i];
                float av = ((const float*)&zFijv)[r] - dot4(bq[r], zHcjv);
                float ap = tf[r] - dot4(bq[r], hpcv);
                sA[i*20 + j]  = av;
                sAP[i*20 + j] = ap;
            }
            rbtv = make_float4(dot4(zR4[0], bj), dot4(zR4[1], bj),
                               dot4(zR4[2], bj), dot4(zR4[3], bj));
        }
        __syncthreads();

        // ---- s5: P' = AP*A^T + B*rbt + Q (Joseph) + FUSED FILTER step ----
        float4 zA[4];
#pragma unroll
        for (int f = 0; f < 4; ++f) zA[f] = sA4[j*5 + f];   // A row j (= filter row i)
        float dmax = 0.f;
#pragma unroll
        for (int r = 0; r < 4; ++r) {
            int i = q + 4*r;
            float acc = zQ[r] + dot4(bq[r], rbtv);
#pragma unroll
            for (int f = 0; f < 4; ++f) acc += dot4(sAP4[i*5 + f], zA[f]);
            float po = sP[i*20 + j];
            sP[i*20 + j] = acc;
            dmax = fmaxf(dmax, fabsf(acc - po));
        }
        // filter: out[t] = H z_t ; z <- A_t z + B_t obs_t   (lane (g=q, i=j))
        {
            float arr[16] = {zA[0].x,zA[0].y,zA[0].z,zA[0].w,
                             zA[1].x,zA[1].y,zA[1].z,zA[1].w,
                             zA[2].x,zA[2].y,zA[2].z,zA[2].w,
                             zA[3].x,zA[3].y,zA[3].z,zA[3].w};
            float4 bb = sB4[j];
            float4 oo = sObs4[q*256 + t];
            float o = 0.f, zn = dot4(bb, oo);
#pragma unroll
            for (int k = 0; k < 16; ++k) {
                float zk = __shfl(zr, gbase + k);
                o  = fmaf(hr[k],  zk, o);
                zn = fmaf(arr[k], zk, zn);
            }
            if (j < 4) sOut[(q*256 + t)*4 + j] = o;
            zr = zn;
            __syncthreads();   // sP ready for next s1; sB/sA reads done
            if (t >= CONV_TMIN && __all(dmax < CONV_EPS)) {
#pragma unroll
                for (int k = 0; k < 16; ++k) arF[k] = arr[k];
                bbF = bb;
                frozen = true;
                ++t;
                break;
            }
        }
    }

    // ---- frozen tail: A/B constant in regs, no LDS writes, no barriers ----
    if (frozen) {
        for (int tt = t; tt < NSTEP; ++tt) {
            float4 oo = sObs4[q*256 + tt];
            float o = 0.f, zn = dot4(bbF, oo);
#pragma unroll
            for (int k = 0; k < 16; ++k) {
                float zk = __shfl(zr, gbase + k);
                o  = fmaf(hr[k],  zk, o);
                zn = fmaf(arF[k], zk, zn);
            }
            if (j < 4) sOut[(q*256 + tt)*4 + j] = o;
            zr = zn;
        }
    }
    // ---- final output: out[255] = H z_255 ----
    {
        float o = 0.f;
#pragma unroll
        for (int k = 0; k < 16; ++k) {
            float zk = __shfl(zr, gbase + k);
            o = fmaf(hr[k], zk, o);
        }
        if (j < 4) sOut[(q*256 + 255)*4 + j] = o;
    }
    __syncthreads();
    // ---- flush out: 4 batches x 256 steps, coalesced float4 runs ----
    float4* out4 = (float4*)out;
    for (int u = tid; u < 1024; u += 64)
        out4[(blockIdx.x * 4 + (u >> 8)) * NT + (u & 255)] = sOut4[u];
}

extern "C" void kernel_launch(void* const* d_in, const int* in_sizes, int n_in,
                              void* d_out, int out_size, void* d_ws, size_t ws_size,
                              hipStream_t stream) {
    const float* obs = (const float*)d_in[0];   // [B,T,M]
    const float* F   = (const float*)d_in[1];   // [S,S]
    const float* H   = (const float*)d_in[2];   // [M,S]
    const float* Q   = (const float*)d_in[3];   // [S,S]
    const float* R   = (const float*)d_in[4];   // [M,M]
    const float* x0  = (const float*)d_in[5];   // [S]
    const float* sd  = (const float*)d_in[6];   // [S]
    float* out = (float*)d_out;

    hipLaunchKernelGGL(kf_block_kernel, dim3(256), dim3(64), 0, stream,
                       obs, F, H, Q, R, x0, sd, out);
}